// Round 2
// baseline (625.838 us; speedup 1.0000x reference)
//
#include <hip/hip_runtime.h>
#include <hip/hip_bf16.h>

#define NFEAT 128
#define HID 16
#define NACT 18
#define NGRAPH 64

// ---------- CSR build ----------
__global__ __launch_bounds__(256) void k_hist(int* __restrict__ cnt,
                                              const int* __restrict__ dst, int E) {
    int e = blockIdx.x * 256 + threadIdx.x;
    if (e < E) atomicAdd(&cnt[dst[e]], 1);
}

// block scans 1024 elements (256 threads x 4)
__global__ __launch_bounds__(256) void k_scan1(const int* __restrict__ cnt,
                                               int* __restrict__ rowptr,
                                               int* __restrict__ partials, int N) {
    __shared__ int ts[256];
    int t = threadIdx.x;
    int base = blockIdx.x * 1024 + t * 4;
    int v0 = base + 0 < N ? cnt[base + 0] : 0;
    int v1 = base + 1 < N ? cnt[base + 1] : 0;
    int v2 = base + 2 < N ? cnt[base + 2] : 0;
    int v3 = base + 3 < N ? cnt[base + 3] : 0;
    int s = v0 + v1 + v2 + v3;
    ts[t] = s;
    __syncthreads();
    for (int off = 1; off < 256; off <<= 1) {
        int tmp = (t >= off) ? ts[t - off] : 0;
        __syncthreads();
        ts[t] += tmp;
        __syncthreads();
    }
    if (t == 255) partials[blockIdx.x] = ts[255];
    int run = ts[t] - s;   // exclusive prefix of this thread
    if (base + 0 < N) rowptr[base + 0] = run; run += v0;
    if (base + 1 < N) rowptr[base + 1] = run; run += v1;
    if (base + 2 < N) rowptr[base + 2] = run; run += v2;
    if (base + 3 < N) rowptr[base + 3] = run;
}

__global__ __launch_bounds__(128) void k_scan2(int* __restrict__ partials, int P) {
    __shared__ int ts[128];
    int t = threadIdx.x;
    int v = (t < P) ? partials[t] : 0;
    ts[t] = v;
    __syncthreads();
    for (int off = 1; off < 128; off <<= 1) {
        int tmp = (t >= off) ? ts[t - off] : 0;
        __syncthreads();
        ts[t] += tmp;
        __syncthreads();
    }
    if (t < P) partials[t] = ts[t] - v;   // exclusive
}

__global__ __launch_bounds__(256) void k_scan3(int* __restrict__ rowptr,
                                               int* __restrict__ cursor,
                                               const int* __restrict__ partials,
                                               int N, int E) {
    int i = blockIdx.x * 256 + threadIdx.x;
    if (i < N) {
        int r = rowptr[i] + partials[i >> 10];
        rowptr[i] = r;
        cursor[i] = r;
        if (i == 0) rowptr[N] = E;
    }
}

__global__ __launch_bounds__(256) void k_scatter(int2* __restrict__ edata,
                                                 int* __restrict__ cursor,
                                                 const int* __restrict__ src,
                                                 const int* __restrict__ dst,
                                                 const float* __restrict__ w, int E) {
    int e = blockIdx.x * 256 + threadIdx.x;
    if (e < E) {
        int d = dst[e];
        int pos = atomicAdd(&cursor[d], 1);
        edata[pos] = make_int2(src[e], __float_as_int(w[e]));
    }
}

// dinv[n] = rsqrt(1 + sum_w over CSR row) -- 16 lanes per node, shuffle-reduce
__global__ __launch_bounds__(256) void k_dinv_csr(float* __restrict__ dinv,
                                                  const int2* __restrict__ edata,
                                                  const int* __restrict__ rowptr, int N) {
    int gid = blockIdx.x * 256 + threadIdx.x;
    int n = gid >> 4, j = gid & 15;
    if (n >= N) return;
    int beg = rowptr[n], end = rowptr[n + 1];
    float s = 0.f;
    for (int p = beg + j; p < end; p += 16) s += __int_as_float(edata[p].y);
    s += __shfl_xor(s, 1, 16);
    s += __shfl_xor(s, 2, 16);
    s += __shfl_xor(s, 4, 16);
    s += __shfl_xor(s, 8, 16);
    if (j == 0) dinv[n] = rsqrtf(1.0f + s);
}

// ---------- dense transform 1: h = x @ W1 ----------
__global__ __launch_bounds__(256) void k_gemm1(const float* __restrict__ x,
                                               const float* __restrict__ W1,
                                               float* __restrict__ h) {
    __shared__ float xs[16 * 132];
    __shared__ float ws[NFEAT * HID];
    int t = threadIdx.x;
    for (int i = t; i < NFEAT * HID; i += 256) ws[i] = W1[i];
    const float* xblk = x + (size_t)blockIdx.x * 16 * NFEAT;
    #pragma unroll
    for (int rep = 0; rep < 2; rep++) {
        int i4 = (rep * 256 + t) * 4;
        int row = i4 >> 7, col = i4 & 127;
        float4 v = *reinterpret_cast<const float4*>(xblk + i4);
        *reinterpret_cast<float4*>(&xs[row * 132 + col]) = v;
    }
    __syncthreads();
    int r = t >> 4, j = t & 15;
    float acc = 0.f;
    #pragma unroll
    for (int k = 0; k < NFEAT; k++) acc += xs[r * 132 + k] * ws[k * HID + j];
    h[((size_t)blockIdx.x * 16 + r) * HID + j] = acc;
}

// ---------- layer1 aggregate + bias + relu + @W2, fused ----------
// h2[n][j] = sum_k relu(agg1[n][k] + dinv^2 h[n][k] + b1[k]) * W2[k][j]
__global__ __launch_bounds__(256) void k_agg1(const float* __restrict__ h,
                                              const int2* __restrict__ edata,
                                              const int* __restrict__ rowptr,
                                              const float* __restrict__ dinv,
                                              const float* __restrict__ b1,
                                              const float* __restrict__ W2,
                                              float* __restrict__ h2, int N) {
    __shared__ float act[16][17];
    __shared__ float w2s[16][16];
    int t = threadIdx.x;
    w2s[t >> 4][t & 15] = W2[t];
    int r = t >> 4, j = t & 15;
    int n = blockIdx.x * 16 + r;
    if (n < N) {
        float dv = dinv[n];
        int beg = rowptr[n], end = rowptr[n + 1];
        float acc = 0.f;
        for (int p = beg; p < end; ++p) {
            int2 ed = edata[p];
            float nr = dv * __int_as_float(ed.y) * dinv[ed.x];
            acc += nr * h[ed.x * HID + j];
        }
        float pre = acc + dv * dv * h[n * HID + j] + b1[j];
        act[r][j] = pre > 0.f ? pre : 0.f;
    }
    __syncthreads();
    if (n < N) {
        float o = 0.f;
        #pragma unroll
        for (int k = 0; k < HID; k++) o += act[r][k] * w2s[k][j];
        h2[n * HID + j] = o;
    }
}

// ---------- layer2 aggregate + bias + relu + global max pool, fused ----------
__global__ __launch_bounds__(256) void k_agg2_pool(const float* __restrict__ h2,
                                                   const int2* __restrict__ edata,
                                                   const int* __restrict__ rowptr,
                                                   const float* __restrict__ dinv,
                                                   const float* __restrict__ b2,
                                                   const int* __restrict__ batch,
                                                   unsigned* __restrict__ pooled, int N) {
    __shared__ unsigned pl[NGRAPH * HID];
    int t = threadIdx.x;
    #pragma unroll
    for (int i = t; i < NGRAPH * HID; i += 256) pl[i] = 0u;
    __syncthreads();
    int r = t >> 4, j = t & 15;
    int n = blockIdx.x * 16 + r;
    if (n < N) {
        float dv = dinv[n];
        int beg = rowptr[n], end = rowptr[n + 1];
        float acc = 0.f;
        for (int p = beg; p < end; ++p) {
            int2 ed = edata[p];
            float nr = dv * __int_as_float(ed.y) * dinv[ed.x];
            acc += nr * h2[ed.x * HID + j];
        }
        float v = acc + dv * dv * h2[n * HID + j] + b2[j];
        v = v > 0.f ? v : 0.f;
        atomicMax(&pl[batch[n] * HID + j], __float_as_uint(v));
    }
    __syncthreads();
    for (int i = t; i < NGRAPH * HID; i += 256) {
        unsigned b = pl[i];
        if (b) atomicMax(&pooled[i], b);
    }
}

__global__ __launch_bounds__(256) void k_final(const unsigned* __restrict__ pooled,
                                               const float* __restrict__ Wl,
                                               const float* __restrict__ bl,
                                               float* __restrict__ out) {
    int gid = blockIdx.x * 256 + threadIdx.x;
    if (gid < NGRAPH * NACT) {
        int g = gid / NACT, a = gid - g * NACT;
        float acc = bl[a];
        #pragma unroll
        for (int k = 0; k < HID; k++)
            acc += __uint_as_float(pooled[g * HID + k]) * Wl[k * NACT + a];
        out[gid] = acc;
    }
}

extern "C" void kernel_launch(void* const* d_in, const int* in_sizes, int n_in,
                              void* d_out, int out_size, void* d_ws, size_t ws_size,
                              hipStream_t stream) {
    const float* x     = (const float*)d_in[0];
    const int*   ei    = (const int*)d_in[1];
    const float* ew    = (const float*)d_in[2];
    const int*   batch = (const int*)d_in[3];
    const float* W1    = (const float*)d_in[4];
    const float* b1    = (const float*)d_in[5];
    const float* W2    = (const float*)d_in[6];
    const float* b2    = (const float*)d_in[7];
    const float* Wl    = (const float*)d_in[8];
    const float* bl    = (const float*)d_in[9];
    float* out = (float*)d_out;

    int N = in_sizes[0] / NFEAT;
    int E = in_sizes[1] / 2;
    const int* srcIdx = ei;
    const int* dstIdx = ei + E;

    // workspace layout (edata first for 8B alignment)
    int2*  edata  = (int2*)d_ws;                       // [E]
    float* dinv   = (float*)(edata + E);               // [N]
    float* h      = dinv + N;                          // [N*HID]
    float* h2     = h + (size_t)N * HID;               // [N*HID]
    int*   rowptr = (int*)(h2 + (size_t)N * HID);      // [N+1]
    int*   cursor = rowptr + N + 1;                    // [N]
    int*   cnt    = cursor + N;                        // [N]
    int*   partials = cnt + N;                         // [256]
    unsigned* pooled = (unsigned*)(partials + 256);    // [NGRAPH*HID]

    int nbN  = (N + 255) / 256;
    int nbE  = (E + 255) / 256;
    int nbNH = (int)(((long long)N * HID + 255) / 256);
    int nb16 = (N + 15) / 16;
    int NB1  = (N + 1023) / 1024;

    hipMemsetAsync(cnt, 0, (size_t)N * sizeof(int), stream);
    hipMemsetAsync(pooled, 0, NGRAPH * HID * sizeof(unsigned), stream);

    // CSR build
    k_hist   <<<nbE, 256, 0, stream>>>(cnt, dstIdx, E);
    k_scan1  <<<NB1, 256, 0, stream>>>(cnt, rowptr, partials, N);
    k_scan2  <<<1, 128, 0, stream>>>(partials, NB1);
    k_scan3  <<<nbN, 256, 0, stream>>>(rowptr, cursor, partials, N, E);
    k_scatter<<<nbE, 256, 0, stream>>>(edata, cursor, srcIdx, dstIdx, ew, E);
    k_dinv_csr<<<nbNH, 256, 0, stream>>>(dinv, edata, rowptr, N);

    // dense + fused layers
    k_gemm1    <<<N / 16, 256, 0, stream>>>(x, W1, h);
    k_agg1     <<<nb16, 256, 0, stream>>>(h, edata, rowptr, dinv, b1, W2, h2, N);
    k_agg2_pool<<<nb16, 256, 0, stream>>>(h2, edata, rowptr, dinv, b2, batch, pooled, N);
    k_final    <<<(NGRAPH * NACT + 255) / 256, 256, 0, stream>>>(pooled, Wl, bl, out);
}